// Round 1
// baseline (96.778 us; speedup 1.0000x reference)
//
#include <hip/hip_runtime.h>
#include <stdint.h>

// Problem constants
#define NSLICE 64          // B*C = 16*4
#define N_ELEM 262144      // D*H*W = 64^3 per slice
#define K_TOP  131072      // ceil(0.5*N)
#define BATCH_B 16.0f

#define NB1    4096        // level-1 buckets: bits 31..20 of bits(|d|)
#define SHIFT1 20
#define NB2    4096        // level-2 buckets: bits 19..8
#define SHIFT2 8
#define CPB    32          // chunks (blocks) per slice for the big passes
#define CHUNK  (N_ELEM / CPB)   // 8192 elements per block
#define BLK    256

__device__ __forceinline__ unsigned int absbits(float d) {
    return __float_as_uint(d) & 0x7fffffffu;
}

// ---------------- Pass 1: level-1 count histogram per slice ----------------
__global__ __launch_bounds__(BLK) void k_pass1(const float* __restrict__ in,
                                               const float* __restrict__ lab,
                                               unsigned int* __restrict__ hist1) {
    __shared__ unsigned int h[NB1];
    const int tid = threadIdx.x;
    for (int i = tid; i < NB1; i += BLK) h[i] = 0;
    __syncthreads();

    const int slice = blockIdx.y;
    const long base = (long)slice * N_ELEM + (long)blockIdx.x * CHUNK;
    const float4* a4 = (const float4*)(in + base);
    const float4* b4 = (const float4*)(lab + base);
    const int nv = CHUNK / 4;  // 2048
    for (int i = tid; i < nv; i += BLK) {
        float4 a = a4[i];
        float4 b = b4[i];
        float d0 = a.x - b.x, d1 = a.y - b.y, d2 = a.z - b.z, d3 = a.w - b.w;
        atomicAdd(&h[absbits(d0) >> SHIFT1], 1u);
        atomicAdd(&h[absbits(d1) >> SHIFT1], 1u);
        atomicAdd(&h[absbits(d2) >> SHIFT1], 1u);
        atomicAdd(&h[absbits(d3) >> SHIFT1], 1u);
    }
    __syncthreads();
    unsigned int* gh = hist1 + (long)slice * NB1;
    for (int i = tid; i < NB1; i += BLK) {
        unsigned int c = h[i];
        if (c) atomicAdd(&gh[i], c);
    }
}

// ------------- Select 1: find threshold bucket b1 + residual r1 ------------
// br[slice*2] = b1, br[slice*2+1] = r1  (1 <= r1 <= count(b1))
__global__ __launch_bounds__(BLK) void k_select1(const unsigned int* __restrict__ hist1,
                                                 unsigned int* __restrict__ br) {
    const int slice = blockIdx.x;
    const unsigned int* gh = hist1 + (long)slice * NB1;
    __shared__ unsigned int part[BLK];
    __shared__ unsigned int pref[BLK];
    const int t = threadIdx.x;
    const int G = NB1 / BLK;  // 16 buckets per thread, descending order
    unsigned int loc[NB1 / BLK];
    unsigned int s = 0;
    for (int j = 0; j < G; ++j) {
        loc[j] = gh[NB1 - 1 - (t * G + j)];
        s += loc[j];
    }
    part[t] = s;
    __syncthreads();
    if (t == 0) {
        unsigned int c = 0;
        for (int i = 0; i < BLK; ++i) { pref[i] = c; c += part[i]; }
    }
    __syncthreads();
    unsigned int cum = pref[t];
    for (int j = 0; j < G; ++j) {
        unsigned int nc = cum + loc[j];
        if (cum < K_TOP && nc >= K_TOP) {
            br[slice * 2 + 0] = (unsigned int)(NB1 - 1 - (t * G + j));
            br[slice * 2 + 1] = K_TOP - cum;  // >= 1
        }
        cum = nc;
    }
}

// --- Pass 2: exact sumsq above b1; level-2 count+sumsq hist inside b1 ------
__global__ __launch_bounds__(BLK) void k_pass2(const float* __restrict__ in,
                                               const float* __restrict__ lab,
                                               const unsigned int* __restrict__ br,
                                               unsigned int* __restrict__ hist2c,
                                               float* __restrict__ hist2s,
                                               float* __restrict__ sliceAbove) {
    __shared__ unsigned int hc[NB2];
    __shared__ float hs[NB2];
    const int tid = threadIdx.x;
    for (int i = tid; i < NB2; i += BLK) { hc[i] = 0; hs[i] = 0.0f; }
    __syncthreads();

    const int slice = blockIdx.y;
    const unsigned int b1 = br[slice * 2 + 0];
    const long base = (long)slice * N_ELEM + (long)blockIdx.x * CHUNK;
    const float4* a4 = (const float4*)(in + base);
    const float4* b4 = (const float4*)(lab + base);
    const int nv = CHUNK / 4;
    float above = 0.0f;
    for (int i = tid; i < nv; i += BLK) {
        float4 a = a4[i];
        float4 b = b4[i];
        float d[4] = {a.x - b.x, a.y - b.y, a.z - b.z, a.w - b.w};
#pragma unroll
        for (int j = 0; j < 4; ++j) {
            unsigned int u = absbits(d[j]);
            unsigned int p = u >> SHIFT1;
            if (p > b1) {
                above += d[j] * d[j];
            } else if (p == b1) {
                unsigned int sub = (u >> SHIFT2) & (NB2 - 1);
                atomicAdd(&hc[sub], 1u);
                atomicAdd(&hs[sub], d[j] * d[j]);
            }
        }
    }
    // block-reduce 'above'
    __shared__ float red[BLK / 64];
#pragma unroll
    for (int off = 32; off > 0; off >>= 1) above += __shfl_down(above, off);
    const int lane = tid & 63, wid = tid >> 6;
    if (lane == 0) red[wid] = above;
    __syncthreads();
    if (tid == 0) {
        float tot = 0.0f;
        for (int w = 0; w < BLK / 64; ++w) tot += red[w];
        atomicAdd(&sliceAbove[slice], tot);
    }
    __syncthreads();
    unsigned int* gc = hist2c + (long)slice * NB2;
    float* gs = hist2s + (long)slice * NB2;
    for (int i = tid; i < NB2; i += BLK) {
        if (hc[i]) {
            atomicAdd(&gc[i], hc[i]);
            atomicAdd(&gs[i], hs[i]);
        }
    }
}

// -------- Select 2 + finalize: scan level-2, add partial bucket ------------
__global__ __launch_bounds__(BLK) void k_select2(const unsigned int* __restrict__ hist2c,
                                                 const float* __restrict__ hist2s,
                                                 const unsigned int* __restrict__ br,
                                                 const float* __restrict__ sliceAbove,
                                                 float* __restrict__ out) {
    const int slice = blockIdx.x;
    const unsigned int* gc = hist2c + (long)slice * NB2;
    const float* gs = hist2s + (long)slice * NB2;
    const unsigned int r1 = br[slice * 2 + 1];
    __shared__ unsigned int partC[BLK];
    __shared__ float partS[BLK];
    __shared__ unsigned int prefC[BLK];
    __shared__ float prefS[BLK];
    const int t = threadIdx.x;
    const int G = NB2 / BLK;  // 16
    unsigned int locC[NB2 / BLK];
    float locS[NB2 / BLK];
    unsigned int sc = 0;
    float ss = 0.0f;
    for (int j = 0; j < G; ++j) {
        int idx = NB2 - 1 - (t * G + j);
        locC[j] = gc[idx];
        locS[j] = gs[idx];
        sc += locC[j];
        ss += locS[j];
    }
    partC[t] = sc;
    partS[t] = ss;
    __syncthreads();
    if (t == 0) {
        unsigned int c = 0;
        float s = 0.0f;
        for (int i = 0; i < BLK; ++i) {
            prefC[i] = c; prefS[i] = s;
            c += partC[i]; s += partS[i];
        }
    }
    __syncthreads();
    unsigned int cum = prefC[t];
    float sAbove = prefS[t];
    for (int j = 0; j < G; ++j) {
        unsigned int nc = cum + locC[j];
        if (cum < r1 && nc >= r1) {
            unsigned int r2 = r1 - cum;                 // 1..locC[j]
            float meanSq = locS[j] / (float)locC[j];    // locC[j] >= 1 here
            float S = sliceAbove[slice] + sAbove + (float)r2 * meanSq;
            atomicAdd(out, S * (1.0f / ((float)K_TOP * BATCH_B)));
        }
        cum = nc;
        sAbove += locS[j];
    }
}

// ---------------------------------------------------------------------------
extern "C" void kernel_launch(void* const* d_in, const int* in_sizes, int n_in,
                              void* d_out, int out_size, void* d_ws, size_t ws_size,
                              hipStream_t stream) {
    const float* in = (const float*)d_in[0];
    const float* lab = (const float*)d_in[1];
    float* out = (float*)d_out;

    unsigned char* w = (unsigned char*)d_ws;
    // ws layout (all offsets 1 MB aligned where big):
    //  [0,        1 MB)  hist1   : 64 * 4096 u32
    //  [1 MB,     2 MB)  hist2c  : 64 * 4096 u32
    //  [2 MB,     3 MB)  hist2s  : 64 * 4096 f32
    //  [3 MB, 3 MB+256)  sliceAbove : 64 f32
    //  [3 MB+1024, ...)  br      : 64 * 2 u32   (written before read; no memset)
    unsigned int* hist1 = (unsigned int*)(w);
    unsigned int* hist2c = (unsigned int*)(w + (1u << 20));
    float* hist2s = (float*)(w + (2u << 20));
    float* sliceAbove = (float*)(w + (3u << 20));
    unsigned int* br = (unsigned int*)(w + (3u << 20) + 1024);

    hipMemsetAsync(w, 0, (3u << 20) + 256, stream);
    hipMemsetAsync(d_out, 0, sizeof(float), stream);

    dim3 grid(CPB, NSLICE), blk(BLK);
    k_pass1<<<grid, blk, 0, stream>>>(in, lab, hist1);
    k_select1<<<NSLICE, BLK, 0, stream>>>(hist1, br);
    k_pass2<<<grid, blk, 0, stream>>>(in, lab, br, hist2c, hist2s, sliceAbove);
    k_select2<<<NSLICE, BLK, 0, stream>>>(hist2c, hist2s, br, sliceAbove, out);
}